// Round 1
// baseline (2810.612 us; speedup 1.0000x reference)
//
#include <hip/hip_runtime.h>

typedef __bf16 bf16x8 __attribute__((ext_vector_type(8)));
typedef float f32x4 __attribute__((ext_vector_type(4)));

static __device__ __forceinline__ unsigned short f2bf(float f) {
    unsigned u = __builtin_bit_cast(unsigned, f);
    u += 0x7FFFu + ((u >> 16) & 1u);
    return (unsigned short)(u >> 16);
}
static __device__ __forceinline__ float bf2f(unsigned short h) {
    return __builtin_bit_cast(float, ((unsigned)h) << 16);
}

// ---------------------------------------------------------------- prep kernels
__global__ __launch_bounds__(256) void rgcn_cvt_x(const float* __restrict__ x,
                                                  unsigned short* __restrict__ xb,
                                                  int n4) {
    int i = blockIdx.x * 256 + threadIdx.x;
    if (i < n4) {
        float4 v = ((const float4*)x)[i];
        ushort4 o;
        o.x = f2bf(v.x); o.y = f2bf(v.y); o.z = f2bf(v.z); o.w = f2bf(v.w);
        ((ushort4*)xb)[i] = o;
    }
}

// wbT[n][k], n in [0,2304): n<2048 -> weight[n>>8][k][n&255]; else loop_weight[k][n-2048]
__global__ __launch_bounds__(256) void rgcn_build_wbT(const float* __restrict__ w,
                                                      const float* __restrict__ lw,
                                                      unsigned short* __restrict__ wbT) {
    int idx = blockIdx.x * 256 + threadIdx.x;   // 2304*256 total
    int n = idx >> 8;
    int k = idx & 255;
    float v;
    if (n < 2048) {
        int r = n >> 8, o = n & 255;
        v = w[((size_t)r * 256 + k) * 256 + o];
    } else {
        v = lw[(size_t)k * 256 + (n - 2048)];
    }
    wbT[idx] = f2bf(v);
}

// ---------------------------------------------------------------- fused GEMM
// C[M x 2304] = xb[M x 256] @ wbT^T ; n<2048 -> hxb (bf16), n>=2048 -> out (f32, scaled+bias)
#define BM 128
#define BN 128
#define BKK 64

__global__ __launch_bounds__(256) void rgcn_gemm(
    const unsigned short* __restrict__ xb,   // [M][256]
    const unsigned short* __restrict__ wbT,  // [2304][256]
    unsigned short* __restrict__ hxb,        // [M][2048]
    float* __restrict__ out,                 // [M][256]
    const float* __restrict__ bias,          // [256]
    int M)
{
    __shared__ char lds[2 * BM * BKK * 2];   // A tile 16KB + B tile 16KB
    char* Ab = lds;
    char* Bb = lds + BM * BKK * 2;

    const int tid  = threadIdx.x;
    const int lane = tid & 63;
    const int wid  = tid >> 6;
    const int wm   = (wid >> 1) * 64;  // wave row offset in tile
    const int wn   = (wid & 1) * 64;   // wave col offset in tile
    const int m0   = blockIdx.x * BM;
    const int n0   = blockIdx.y * BN;

    f32x4 acc[4][4] = {};

    const int sr = tid >> 3;          // staging row base (0..31)
    const int sc = (tid & 7) * 8;     // staging col (elements)

    for (int kt = 0; kt < 256; kt += BKK) {
        __syncthreads();
        #pragma unroll
        for (int it = 0; it < 4; ++it) {
            int r  = sr + it * 32;
            int byteoff = ((r * (BKK * 2) + sc * 2)) ^ ((r & 7) << 4);
            // A tile (guard M tail)
            int gr = m0 + r;
            int4 va = {0, 0, 0, 0};
            if (gr < M) va = *(const int4*)(xb + (size_t)gr * 256 + kt + sc);
            *(int4*)(Ab + byteoff) = va;
            // B tile (2304 is a multiple of 128 -> no guard)
            int nr = n0 + r;
            int4 vb = *(const int4*)(wbT + (size_t)nr * 256 + kt + sc);
            *(int4*)(Bb + byteoff) = vb;
        }
        __syncthreads();
        #pragma unroll
        for (int kk = 0; kk < 2; ++kk) {
            const int koff = kk * 32 + (lane >> 4) * 8;   // element offset within BK row
            bf16x8 af[4], bf[4];
            #pragma unroll
            for (int i = 0; i < 4; ++i) {
                int ar = wm + i * 16 + (lane & 15);
                af[i] = *(const bf16x8*)(Ab + ((ar * (BKK * 2) + koff * 2) ^ ((ar & 7) << 4)));
                int br = wn + i * 16 + (lane & 15);
                bf[i] = *(const bf16x8*)(Bb + ((br * (BKK * 2) + koff * 2) ^ ((br & 7) << 4)));
            }
            #pragma unroll
            for (int i = 0; i < 4; ++i)
                #pragma unroll
                for (int j = 0; j < 4; ++j)
                    acc[i][j] = __builtin_amdgcn_mfma_f32_16x16x32_bf16(af[i], bf[j], acc[i][j], 0, 0, 0);
        }
    }

    // epilogue: D mapping col=lane&15, row=(lane>>4)*4+reg  [m89-verified]
    const int col = lane & 15;
    const int r0  = (lane >> 4) * 4;
    if (n0 < 2048) {
        #pragma unroll
        for (int i = 0; i < 4; ++i) {
            #pragma unroll
            for (int j = 0; j < 4; ++j) {
                int gn = n0 + wn + j * 16 + col;
                #pragma unroll
                for (int rr = 0; rr < 4; ++rr) {
                    int gm = m0 + wm + i * 16 + r0 + rr;
                    if (gm < M) hxb[(size_t)gm * 2048 + gn] = f2bf(acc[i][j][rr]);
                }
            }
        }
    } else {
        const float s = 0.70710678118654752f;  // sqrt(1-ALPHA)
        #pragma unroll
        for (int i = 0; i < 4; ++i) {
            #pragma unroll
            for (int j = 0; j < 4; ++j) {
                int gn = n0 + wn + j * 16 + col - 2048;
                float bv = bias[gn];
                #pragma unroll
                for (int rr = 0; rr < 4; ++rr) {
                    int gm = m0 + wm + i * 16 + r0 + rr;
                    if (gm < M) out[(size_t)gm * 256 + gn] = acc[i][j][rr] * s + bv;
                }
            }
        }
    }
}

// ---------------------------------------------------------------- edge scatter
// one wave per edge: gather hxb[src, type] (512B bf16), scale by sqrt(ALPHA),
// atomicAdd f32 into out[dst]
__global__ __launch_bounds__(256) void rgcn_edge(
    const int* __restrict__ ei,   // [2][E]
    const int* __restrict__ et,   // [E]
    const unsigned short* __restrict__ hxb,
    float* __restrict__ out,
    int E)
{
    int gw   = (blockIdx.x * 256 + threadIdx.x) >> 6;
    int lane = threadIdx.x & 63;
    int nw   = (gridDim.x * 256) >> 6;
    const float s = 0.70710678118654752f;  // sqrt(ALPHA)
    for (int e = gw; e < E; e += nw) {
        int src = ei[e];
        int dst = ei[E + e];
        int r   = et[e];
        const ushort4 v = *(const ushort4*)(hxb + (size_t)src * 2048 + (size_t)r * 256 + lane * 4);
        float* orow = out + (size_t)dst * 256 + lane * 4;
        unsafeAtomicAdd(orow + 0, bf2f(v.x) * s);
        unsafeAtomicAdd(orow + 1, bf2f(v.y) * s);
        unsafeAtomicAdd(orow + 2, bf2f(v.z) * s);
        unsafeAtomicAdd(orow + 3, bf2f(v.w) * s);
    }
}

// ---------------------------------------------------------------- launch
extern "C" void kernel_launch(void* const* d_in, const int* in_sizes, int n_in,
                              void* d_out, int out_size, void* d_ws, size_t ws_size,
                              hipStream_t stream) {
    const int*   edge_index = (const int*)d_in[0];   // [2][E]
    const float* x          = (const float*)d_in[1]; // [M][256]
    const int*   edge_type  = (const int*)d_in[2];   // [E]
    const float* weight     = (const float*)d_in[3]; // [8][256][256]
    const float* h_bias     = (const float*)d_in[4]; // [256]
    const float* loop_w     = (const float*)d_in[5]; // [256][256]
    float* out = (float*)d_out;

    const int M = in_sizes[1] / 256;   // 50000
    const int E = in_sizes[2];         // 800000

    // workspace layout (256B aligned)
    char* ws = (char*)d_ws;
    size_t off = 0;
    unsigned short* xb  = (unsigned short*)(ws + off);
    off += ((size_t)M * 256 * 2 + 255) & ~(size_t)255;
    unsigned short* wbT = (unsigned short*)(ws + off);
    off += ((size_t)2304 * 256 * 2 + 255) & ~(size_t)255;
    unsigned short* hxb = (unsigned short*)(ws + off);
    // off += (size_t)M * 2048 * 2;  // total ~231.6 MB

    // 1) convert x to bf16
    {
        int n4 = (M * 256) / 4;
        rgcn_cvt_x<<<(n4 + 255) / 256, 256, 0, stream>>>(x, xb, n4);
    }
    // 2) build transposed bf16 weight table
    rgcn_build_wbT<<<2304, 256, 0, stream>>>(weight, loop_w, wbT);
    // 3) fused GEMM: hxb (8 relations) + out init (loop + bias)
    {
        dim3 grid((M + BM - 1) / BM, 2304 / BN);
        rgcn_gemm<<<grid, 256, 0, stream>>>(xb, wbT, hxb, out, h_bias, M);
    }
    // 4) edge gather + atomic scatter
    rgcn_edge<<<4096, 256, 0, stream>>>(edge_index, edge_type, hxb, out, E);
}

// Round 2
// 434.668 us; speedup vs baseline: 6.4661x; 6.4661x over previous
//
#include <hip/hip_runtime.h>

typedef __bf16 bf16x8 __attribute__((ext_vector_type(8)));
typedef float f32x4 __attribute__((ext_vector_type(4)));

static __device__ __forceinline__ unsigned short f2bf(float f) {
    unsigned u = __builtin_bit_cast(unsigned, f);
    u += 0x7FFFu + ((u >> 16) & 1u);
    return (unsigned short)(u >> 16);
}
static __device__ __forceinline__ float bf2f(unsigned short h) {
    return __builtin_bit_cast(float, ((unsigned)h) << 16);
}

// ---------------------------------------------------------------- tiny utils
__global__ __launch_bounds__(256) void rgcn_zero(unsigned* __restrict__ p, int n) {
    int i = blockIdx.x * 256 + threadIdx.x;
    if (i < n) p[i] = 0;
}

// histogram of dst
__global__ __launch_bounds__(256) void rgcn_hist(const int* __restrict__ ei,
                                                 unsigned* __restrict__ cnt, int E) {
    int e = blockIdx.x * 256 + threadIdx.x;
    if (e < E) atomicAdd(&cnt[ei[E + e]], 1u);
}

// exclusive scan over cnt[0..n): off[i]=excl, cnt[i]=excl (becomes cursor), off[n]=total
__global__ __launch_bounds__(1024) void rgcn_scan(unsigned* __restrict__ cnt,
                                                  unsigned* __restrict__ off, int n) {
    __shared__ unsigned wsum[16];
    __shared__ unsigned carry_s;
    const int t = threadIdx.x, lane = t & 63, wid = t >> 6;
    if (t == 0) carry_s = 0;
    __syncthreads();
    for (int base = 0; base < n; base += 1024) {
        int i = base + t;
        unsigned v = (i < n) ? cnt[i] : 0;
        unsigned s = v;
        #pragma unroll
        for (int d = 1; d < 64; d <<= 1) {
            unsigned u = __shfl_up(s, d, 64);
            if (lane >= d) s += u;
        }
        if (lane == 63) wsum[wid] = s;
        __syncthreads();
        unsigned wpre = 0;
        #pragma unroll
        for (int j = 0; j < 15; ++j) wpre += (j < wid) ? wsum[j] : 0;
        unsigned carry = carry_s;
        unsigned excl = carry + wpre + s - v;
        if (i < n) { off[i] = excl; cnt[i] = excl; }
        __syncthreads();
        if (t == 1023) carry_s = carry + wpre + s;
        __syncthreads();
    }
    if (t == 0) off[n] = carry_s;
}

// scatter packed records (src | rel<<16) into dst-sorted order
__global__ __launch_bounds__(256) void rgcn_scatter(const int* __restrict__ ei,
                                                    const int* __restrict__ et,
                                                    unsigned* __restrict__ cur,
                                                    unsigned* __restrict__ recs, int E) {
    int e = blockIdx.x * 256 + threadIdx.x;
    if (e < E) {
        int dst = ei[E + e];
        unsigned p = atomicAdd(&cur[dst], 1u);
        recs[p] = (unsigned)ei[e] | ((unsigned)et[e] << 16);
    }
}

// write bf16 x into Zcat columns 2048..2303 (one wave per node row)
__global__ __launch_bounds__(256) void rgcn_cvt(const float* __restrict__ x,
                                                unsigned short* __restrict__ Z, int M) {
    int w = (blockIdx.x * 256 + threadIdx.x) >> 6;
    int lane = threadIdx.x & 63;
    if (w >= M) return;
    float4 v = *(const float4*)(x + (size_t)w * 256 + lane * 4);
    ushort4 o;
    o.x = f2bf(v.x); o.y = f2bf(v.y); o.z = f2bf(v.z); o.w = f2bf(v.w);
    *(ushort4*)(Z + (size_t)w * 2304 + 2048 + lane * 4) = o;
}

// wbT[n][kc]: kc<2048 -> sqrt(a)*weight[kc>>8][kc&255][n]; else sqrt(1-a)*loop_w[kc-2048][n]
__global__ __launch_bounds__(256) void rgcn_wbt(const float* __restrict__ w,
                                                const float* __restrict__ lw,
                                                unsigned short* __restrict__ wbT) {
    int kc = blockIdx.x * 256 + threadIdx.x;   // 0..2303
    int n  = blockIdx.y;                       // 0..255
    if (kc >= 2304) return;
    float v;
    if (kc < 2048) {
        int r = kc >> 8, k = kc & 255;
        v = w[((size_t)r * 256 + k) * 256 + n];
    } else {
        v = lw[(size_t)(kc - 2048) * 256 + n];
    }
    wbT[(size_t)n * 2304 + kc] = f2bf(v * 0.70710678118654752f);  // sqrt(0.5) both terms
}

// ---------------------------------------------------------------- aggregation
// one wave per dst node: sum bf16 x rows per relation into registers, write 8 Z rows
__global__ __launch_bounds__(256) void rgcn_agg(const unsigned* __restrict__ recs,
                                                const unsigned* __restrict__ off,
                                                unsigned short* __restrict__ Z, int M) {
    int w = (blockIdx.x * 256 + threadIdx.x) >> 6;
    int lane = threadIdx.x & 63;
    if (w >= M) return;
    unsigned o0 = off[w], o1 = off[w + 1];
    f32x4 a0 = {}, a1 = {}, a2 = {}, a3 = {}, a4 = {}, a5 = {}, a6 = {}, a7 = {};

#define LOADF(rec, fv)                                                                 \
    {                                                                                  \
        const ushort4 v_ = *(const ushort4*)(Z + (size_t)((rec) & 0xFFFFu) * 2304 +    \
                                             2048 + lane * 4);                         \
        fv[0] = bf2f(v_.x); fv[1] = bf2f(v_.y); fv[2] = bf2f(v_.z); fv[3] = bf2f(v_.w);\
    }
#define ACCUM(rec, fv)                                                                 \
    switch ((rec) >> 16) {                                                             \
        case 0: a0 += fv; break; case 1: a1 += fv; break;                              \
        case 2: a2 += fv; break; case 3: a3 += fv; break;                              \
        case 4: a4 += fv; break; case 5: a5 += fv; break;                              \
        case 6: a6 += fv; break; default: a7 += fv; break;                             \
    }

    unsigned i = o0;
    for (; i + 1 < o1; i += 2) {   // 2-wide for gather ILP
        unsigned r0 = recs[i], r1 = recs[i + 1];
        f32x4 f0, f1;
        LOADF(r0, f0);
        LOADF(r1, f1);
        ACCUM(r0, f0);
        ACCUM(r1, f1);
    }
    if (i < o1) {
        unsigned r0 = recs[i];
        f32x4 f0;
        LOADF(r0, f0);
        ACCUM(r0, f0);
    }
#undef LOADF
#undef ACCUM

    unsigned short* zr = Z + (size_t)w * 2304 + lane * 4;
#define ST(rr, ax)                                                                     \
    {                                                                                  \
        ushort4 o_;                                                                    \
        o_.x = f2bf(ax[0]); o_.y = f2bf(ax[1]); o_.z = f2bf(ax[2]); o_.w = f2bf(ax[3]);\
        *(ushort4*)(zr + rr * 256) = o_;                                               \
    }
    ST(0, a0) ST(1, a1) ST(2, a2) ST(3, a3) ST(4, a4) ST(5, a5) ST(6, a6) ST(7, a7)
#undef ST
}

// ---------------------------------------------------------------- GEMM
// out[M x 256] = Zcat[M x 2304] @ wbT^T + bias  (scales pre-folded into wbT)
#define BM 128
#define BN 128
#define BK 64

__global__ __launch_bounds__(256) void rgcn_gemm(
    const unsigned short* __restrict__ A,    // Zcat [M][2304]
    const unsigned short* __restrict__ Bt,   // wbT  [256][2304]
    float* __restrict__ out,                 // [M][256]
    const float* __restrict__ bias,          // [256]
    int M)
{
    __shared__ char lds[2 * BM * BK * 2];
    char* Ab = lds;
    char* Bb = lds + BM * BK * 2;

    const int tid  = threadIdx.x;
    const int lane = tid & 63;
    const int wid  = tid >> 6;
    const int wm   = (wid >> 1) * 64;
    const int wn   = (wid & 1) * 64;
    const int n0   = blockIdx.x * BN;   // 0 or 128
    const int m0   = blockIdx.y * BM;

    f32x4 acc[4][4] = {};

    const int sr = tid >> 3;
    const int sc = (tid & 7) * 8;

    for (int kt = 0; kt < 2304; kt += BK) {
        __syncthreads();
        #pragma unroll
        for (int it = 0; it < 4; ++it) {
            int r = sr + it * 32;
            int byteoff = ((r * (BK * 2) + sc * 2)) ^ ((r & 7) << 4);
            int gr = m0 + r;
            int4 va = {0, 0, 0, 0};
            if (gr < M) va = *(const int4*)(A + (size_t)gr * 2304 + kt + sc);
            *(int4*)(Ab + byteoff) = va;
            int nr = n0 + r;   // < 256 always
            int4 vb = *(const int4*)(Bt + (size_t)nr * 2304 + kt + sc);
            *(int4*)(Bb + byteoff) = vb;
        }
        __syncthreads();
        #pragma unroll
        for (int kk = 0; kk < 2; ++kk) {
            const int koff = kk * 32 + (lane >> 4) * 8;
            bf16x8 af[4], bfr[4];
            #pragma unroll
            for (int i = 0; i < 4; ++i) {
                int ar = wm + i * 16 + (lane & 15);
                af[i] = *(const bf16x8*)(Ab + ((ar * (BK * 2) + koff * 2) ^ ((ar & 7) << 4)));
                int br = wn + i * 16 + (lane & 15);
                bfr[i] = *(const bf16x8*)(Bb + ((br * (BK * 2) + koff * 2) ^ ((br & 7) << 4)));
            }
            #pragma unroll
            for (int i = 0; i < 4; ++i)
                #pragma unroll
                for (int j = 0; j < 4; ++j)
                    acc[i][j] = __builtin_amdgcn_mfma_f32_16x16x32_bf16(af[i], bfr[j], acc[i][j], 0, 0, 0);
        }
    }

    // D mapping: col=lane&15, row=(lane>>4)*4+reg
    const int col = lane & 15;
    const int r0  = (lane >> 4) * 4;
    #pragma unroll
    for (int i = 0; i < 4; ++i) {
        #pragma unroll
        for (int j = 0; j < 4; ++j) {
            int gn = n0 + wn + j * 16 + col;
            float bv = bias[gn];
            #pragma unroll
            for (int rr = 0; rr < 4; ++rr) {
                int gm = m0 + wm + i * 16 + r0 + rr;
                if (gm < M) out[(size_t)gm * 256 + gn] = acc[i][j][rr] + bv;
            }
        }
    }
}

// ---------------------------------------------------------------- launch
extern "C" void kernel_launch(void* const* d_in, const int* in_sizes, int n_in,
                              void* d_out, int out_size, void* d_ws, size_t ws_size,
                              hipStream_t stream) {
    const int*   edge_index = (const int*)d_in[0];   // [2][E]
    const float* x          = (const float*)d_in[1]; // [M][256]
    const int*   edge_type  = (const int*)d_in[2];   // [E]
    const float* weight     = (const float*)d_in[3]; // [8][256][256]
    const float* h_bias     = (const float*)d_in[4]; // [256]
    const float* loop_w     = (const float*)d_in[5]; // [256][256]
    float* out = (float*)d_out;

    const int M = in_sizes[1] / 256;   // 50000
    const int E = in_sizes[2];         // 800000

    // workspace layout (256B aligned): Zcat 230.4MB | wbT 1.18MB | cnt | off | recs
    char* ws = (char*)d_ws;
    size_t off_b = 0;
    unsigned short* Zcat = (unsigned short*)(ws + off_b);
    off_b += (((size_t)M * 2304 * 2) + 255) & ~(size_t)255;
    unsigned short* wbT = (unsigned short*)(ws + off_b);
    off_b += (((size_t)256 * 2304 * 2) + 255) & ~(size_t)255;
    unsigned* cnt = (unsigned*)(ws + off_b);
    off_b += (((size_t)(M + 1) * 4) + 255) & ~(size_t)255;
    unsigned* off = (unsigned*)(ws + off_b);
    off_b += (((size_t)(M + 1) * 4) + 255) & ~(size_t)255;
    unsigned* recs = (unsigned*)(ws + off_b);

    // sort edges by dst (counting sort)
    rgcn_zero<<<(M + 255) / 256, 256, 0, stream>>>(cnt, M);
    rgcn_hist<<<(E + 255) / 256, 256, 0, stream>>>(edge_index, cnt, E);
    rgcn_scan<<<1, 1024, 0, stream>>>(cnt, off, M);
    rgcn_scatter<<<(E + 255) / 256, 256, 0, stream>>>(edge_index, edge_type, cnt, recs, E);

    // bf16 x into Zcat[:, 2048:2304]; weights transposed+scaled
    rgcn_cvt<<<(M + 3) / 4, 256, 0, stream>>>(x, Zcat, M);
    rgcn_wbt<<<dim3(9, 256), 256, 0, stream>>>(weight, loop_w, wbT);

    // per-dst register aggregation -> Zcat[:, 0:2048]
    rgcn_agg<<<(M + 3) / 4, 256, 0, stream>>>(recs, off, Zcat, M);

    // single fused GEMM -> out
    rgcn_gemm<<<dim3(2, (M + BM - 1) / BM), 256, 0, stream>>>(Zcat, wbT, out, h_bias, M);
}

// Round 3
// 338.347 us; speedup vs baseline: 8.3069x; 1.2847x over previous
//
#include <hip/hip_runtime.h>

typedef __bf16 bf16x8 __attribute__((ext_vector_type(8)));
typedef float f32x4 __attribute__((ext_vector_type(4)));

static __device__ __forceinline__ unsigned short f2bf(float f) {
    unsigned u = __builtin_bit_cast(unsigned, f);
    u += 0x7FFFu + ((u >> 16) & 1u);
    return (unsigned short)(u >> 16);
}
static __device__ __forceinline__ float bf2f(unsigned short h) {
    return __builtin_bit_cast(float, ((unsigned)h) << 16);
}

// async 16B global->LDS (linear LDS dest: wave-uniform base + lane*16)
#define GLOAD_LDS16(g, l)                                              \
    __builtin_amdgcn_global_load_lds(                                  \
        (const __attribute__((address_space(1))) unsigned int*)(g),    \
        (__attribute__((address_space(3))) unsigned int*)(l), 16, 0, 0)

// ---------------------------------------------------------------- tiny utils
__global__ __launch_bounds__(256) void rgcn_zero(unsigned* __restrict__ p, int n) {
    int i = blockIdx.x * 256 + threadIdx.x;
    if (i < n) p[i] = 0;
}

// histogram of dst
__global__ __launch_bounds__(256) void rgcn_hist(const int* __restrict__ ei,
                                                 unsigned* __restrict__ cnt, int E) {
    int e = blockIdx.x * 256 + threadIdx.x;
    if (e < E) atomicAdd(&cnt[ei[E + e]], 1u);
}

// ---------------- hierarchical exclusive scan (3 kernels) ----------------
// phase 1: each 1024-thread block scans its 1024 elems; off[i] = local excl; bsum[b]=block total
__global__ __launch_bounds__(1024) void rgcn_scan1(const unsigned* __restrict__ cnt,
                                                   unsigned* __restrict__ off,
                                                   unsigned* __restrict__ bsum, int n) {
    __shared__ unsigned ws[16];
    const int t = threadIdx.x, lane = t & 63, wv = t >> 6;
    int i = blockIdx.x * 1024 + t;
    unsigned v = (i < n) ? cnt[i] : 0;
    unsigned s = v;
    #pragma unroll
    for (int d = 1; d < 64; d <<= 1) {
        unsigned u = __shfl_up(s, d, 64);
        if (lane >= d) s += u;
    }
    if (lane == 63) ws[wv] = s;
    __syncthreads();
    if (wv == 0) {
        unsigned b = (lane < 16) ? ws[lane] : 0;
        unsigned sb = b;
        #pragma unroll
        for (int d = 1; d < 16; d <<= 1) {
            unsigned u = __shfl_up(sb, d, 64);
            if (lane >= d) sb += u;
        }
        if (lane < 16) ws[lane] = sb - b;          // exclusive wave prefix
        if (lane == 15) bsum[blockIdx.x] = sb;     // block total
    }
    __syncthreads();
    if (i < n) off[i] = ws[wv] + (s - v);
}

// phase 2: one wave scans nb (<=64) block sums; writes exclusive bsumo, total -> off[n]
__global__ __launch_bounds__(64) void rgcn_scan2(unsigned* __restrict__ bsum,
                                                 unsigned* __restrict__ bsumo,
                                                 unsigned* __restrict__ off, int nb, int n) {
    const int lane = threadIdx.x & 63;
    unsigned b = (lane < nb) ? bsum[lane] : 0;
    unsigned s = b;
    #pragma unroll
    for (int d = 1; d < 64; d <<= 1) {
        unsigned u = __shfl_up(s, d, 64);
        if (lane >= d) s += u;
    }
    if (lane < nb) bsumo[lane] = s - b;
    if (lane == 63) off[n] = s;
}

// phase 3: add block offsets; copy to cursor
__global__ __launch_bounds__(256) void rgcn_scan3(unsigned* __restrict__ off,
                                                  const unsigned* __restrict__ bsumo,
                                                  unsigned* __restrict__ cur, int n) {
    int i = blockIdx.x * 256 + threadIdx.x;
    if (i < n) {
        unsigned v = off[i] + bsumo[i >> 10];
        off[i] = v;
        cur[i] = v;
    }
}

// scatter packed records (src | rel<<16) into dst-sorted order
__global__ __launch_bounds__(256) void rgcn_scatter(const int* __restrict__ ei,
                                                    const int* __restrict__ et,
                                                    unsigned* __restrict__ cur,
                                                    unsigned* __restrict__ recs, int E) {
    int e = blockIdx.x * 256 + threadIdx.x;
    if (e < E) {
        int dst = ei[E + e];
        unsigned p = atomicAdd(&cur[dst], 1u);
        recs[p] = (unsigned)ei[e] | ((unsigned)et[e] << 16);
    }
}

// write bf16 x into Zcat columns 2048..2303 (one wave per node row)
__global__ __launch_bounds__(256) void rgcn_cvt(const float* __restrict__ x,
                                                unsigned short* __restrict__ Z, int M) {
    int w = (blockIdx.x * 256 + threadIdx.x) >> 6;
    int lane = threadIdx.x & 63;
    if (w >= M) return;
    float4 v = *(const float4*)(x + (size_t)w * 256 + lane * 4);
    ushort4 o;
    o.x = f2bf(v.x); o.y = f2bf(v.y); o.z = f2bf(v.z); o.w = f2bf(v.w);
    *(ushort4*)(Z + (size_t)w * 2304 + 2048 + lane * 4) = o;
}

// wbT[n][kc]: kc<2048 -> weight[kc>>8][kc&255][n]; else loop_w[kc-2048][n]; both * sqrt(0.5)
__global__ __launch_bounds__(256) void rgcn_wbt(const float* __restrict__ w,
                                                const float* __restrict__ lw,
                                                unsigned short* __restrict__ wbT) {
    int kc = blockIdx.x * 256 + threadIdx.x;   // 0..2303
    int n  = blockIdx.y;                       // 0..255
    if (kc >= 2304) return;
    float v;
    if (kc < 2048) {
        int r = kc >> 8, k = kc & 255;
        v = w[((size_t)r * 256 + k) * 256 + n];
    } else {
        v = lw[(size_t)(kc - 2048) * 256 + n];
    }
    wbT[(size_t)n * 2304 + kc] = f2bf(v * 0.70710678118654752f);
}

// ---------------------------------------------------------------- aggregation
// one wave per dst node: sum bf16 x rows per relation into registers, write 8 Z rows
__global__ __launch_bounds__(256) void rgcn_agg(const unsigned* __restrict__ recs,
                                                const unsigned* __restrict__ off,
                                                unsigned short* __restrict__ Z, int M) {
    int w = (blockIdx.x * 256 + threadIdx.x) >> 6;
    int lane = threadIdx.x & 63;
    if (w >= M) return;
    unsigned o0 = off[w], o1 = off[w + 1];
    f32x4 a0 = {}, a1 = {}, a2 = {}, a3 = {}, a4 = {}, a5 = {}, a6 = {}, a7 = {};

    // src fits in 16 bits (M = 50000 < 65536)
#define LOADF(rec, fv)                                                                 \
    {                                                                                  \
        const ushort4 v_ = *(const ushort4*)(Z + (size_t)((rec) & 0xFFFFu) * 2304 +    \
                                             2048 + lane * 4);                         \
        fv[0] = bf2f(v_.x); fv[1] = bf2f(v_.y); fv[2] = bf2f(v_.z); fv[3] = bf2f(v_.w);\
    }
#define ACCUM(rec, fv)                                                                 \
    switch ((rec) >> 16) {                                                             \
        case 0: a0 += fv; break; case 1: a1 += fv; break;                              \
        case 2: a2 += fv; break; case 3: a3 += fv; break;                              \
        case 4: a4 += fv; break; case 5: a5 += fv; break;                              \
        case 6: a6 += fv; break; default: a7 += fv; break;                             \
    }

    unsigned i = o0;
    for (; i + 4 <= o1; i += 4) {   // 4-wide gather ILP
        unsigned r0 = recs[i], r1 = recs[i + 1], r2 = recs[i + 2], r3 = recs[i + 3];
        f32x4 f0, f1, f2, f3;
        LOADF(r0, f0); LOADF(r1, f1); LOADF(r2, f2); LOADF(r3, f3);
        ACCUM(r0, f0); ACCUM(r1, f1); ACCUM(r2, f2); ACCUM(r3, f3);
    }
    for (; i < o1; ++i) {
        unsigned r0 = recs[i];
        f32x4 f0;
        LOADF(r0, f0);
        ACCUM(r0, f0);
    }
#undef LOADF
#undef ACCUM

    unsigned short* zr = Z + (size_t)w * 2304 + lane * 4;
#define ST(rr, ax)                                                                     \
    {                                                                                  \
        ushort4 o_;                                                                    \
        o_.x = f2bf(ax[0]); o_.y = f2bf(ax[1]); o_.z = f2bf(ax[2]); o_.w = f2bf(ax[3]);\
        *(ushort4*)(zr + rr * 256) = o_;                                               \
    }
    ST(0, a0) ST(1, a1) ST(2, a2) ST(3, a3) ST(4, a4) ST(5, a5) ST(6, a6) ST(7, a7)
#undef ST
}

// ---------------------------------------------------------------- GEMM
// out[M x 256] = Zcat[M x 2304] @ wbT^T + bias
// m97 structure: global_load_lds width 16, linear LDS dest, XOR-swizzle via
// pre-swizzled global source (rule 21); swizzled ds_read_b128 (round-2 verified).
#define BM 128
#define BN 128
#define BK 64

__global__ __launch_bounds__(256) void rgcn_gemm(
    const unsigned short* __restrict__ A,    // Zcat [M][2304]
    const unsigned short* __restrict__ Bt,   // wbT  [256][2304]
    float* __restrict__ out,                 // [M][256]
    const float* __restrict__ bias,          // [256]
    int M)
{
    __shared__ char lds[2 * BM * BK * 2];   // A 16KB + B 16KB
    char* Ab = lds;
    char* Bb = lds + BM * BK * 2;

    const int tid  = threadIdx.x;
    const int lane = tid & 63;
    const int wid  = tid >> 6;
    const int wm   = (wid >> 1) * 64;
    const int wn   = (wid & 1) * 64;
    const int n0   = blockIdx.x * BN;   // 0 or 128
    const int m0   = blockIdx.y * BM;

    f32x4 acc[4][4] = {};

    // staging: thread stages 4x16B per tile. chunk o = it*4096 + tid*16;
    // row r = o>>7, dest colbyte cb = o&127, SOURCE colbyte = cb ^ ((r&7)<<4)
    int st_r[4], st_scb[4];
    #pragma unroll
    for (int it = 0; it < 4; ++it) {
        int o = it * 4096 + tid * 16;
        int r = o >> 7;
        st_r[it]   = r;
        st_scb[it] = (o & 127) ^ ((r & 7) << 4);
    }

    for (int kt = 0; kt < 2304; kt += BK) {
        __syncthreads();
        #pragma unroll
        for (int it = 0; it < 4; ++it) {
            const int r = st_r[it], scb = st_scb[it];
            int ga = m0 + r; if (ga >= M) ga = M - 1;          // clamp tail (row discarded at C-write)
            const char* gA = (const char*)A + (size_t)ga * 4608 + (size_t)kt * 2 + scb;
            GLOAD_LDS16(gA, Ab + it * 4096 + tid * 16);
            const char* gB = (const char*)Bt + (size_t)(n0 + r) * 4608 + (size_t)kt * 2 + scb;
            GLOAD_LDS16(gB, Bb + it * 4096 + tid * 16);
        }
        __syncthreads();   // compiler emits s_waitcnt vmcnt(0) before barrier
        #pragma unroll
        for (int kk = 0; kk < 2; ++kk) {
            const int koff = kk * 32 + (lane >> 4) * 8;
            bf16x8 af[4], bfr[4];
            #pragma unroll
            for (int i = 0; i < 4; ++i) {
                int ar = wm + i * 16 + (lane & 15);
                af[i] = *(const bf16x8*)(Ab + ((ar * (BK * 2) + koff * 2) ^ ((ar & 7) << 4)));
                int br = wn + i * 16 + (lane & 15);
                bfr[i] = *(const bf16x8*)(Bb + ((br * (BK * 2) + koff * 2) ^ ((br & 7) << 4)));
            }
            #pragma unroll
            for (int i = 0; i < 4; ++i)
                #pragma unroll
                for (int j = 0; j < 4; ++j)
                    acc[i][j] = __builtin_amdgcn_mfma_f32_16x16x32_bf16(af[i], bfr[j], acc[i][j], 0, 0, 0);
        }
    }

    // D mapping: col=lane&15, row=(lane>>4)*4+reg
    const int col = lane & 15;
    const int r0  = (lane >> 4) * 4;
    #pragma unroll
    for (int i = 0; i < 4; ++i) {
        #pragma unroll
        for (int j = 0; j < 4; ++j) {
            int gn = n0 + wn + j * 16 + col;
            float bv = bias[gn];
            #pragma unroll
            for (int rr = 0; rr < 4; ++rr) {
                int gm = m0 + wm + i * 16 + r0 + rr;
                if (gm < M) out[(size_t)gm * 256 + gn] = acc[i][j][rr] + bv;
            }
        }
    }
}

// ---------------------------------------------------------------- launch
extern "C" void kernel_launch(void* const* d_in, const int* in_sizes, int n_in,
                              void* d_out, int out_size, void* d_ws, size_t ws_size,
                              hipStream_t stream) {
    const int*   edge_index = (const int*)d_in[0];   // [2][E]
    const float* x          = (const float*)d_in[1]; // [M][256]
    const int*   edge_type  = (const int*)d_in[2];   // [E]
    const float* weight     = (const float*)d_in[3]; // [8][256][256]
    const float* h_bias     = (const float*)d_in[4]; // [256]
    const float* loop_w     = (const float*)d_in[5]; // [256][256]
    float* out = (float*)d_out;

    const int M = in_sizes[1] / 256;   // 50000
    const int E = in_sizes[2];         // 800000

    // workspace: Zcat 230.4MB | wbT 1.18MB | cnt | off | bsum | bsumo | recs
    char* ws = (char*)d_ws;
    size_t off_b = 0;
    unsigned short* Zcat = (unsigned short*)(ws + off_b);
    off_b += (((size_t)M * 2304 * 2) + 255) & ~(size_t)255;
    unsigned short* wbT = (unsigned short*)(ws + off_b);
    off_b += (((size_t)256 * 2304 * 2) + 255) & ~(size_t)255;
    unsigned* cnt = (unsigned*)(ws + off_b);
    off_b += (((size_t)(M + 1) * 4) + 255) & ~(size_t)255;
    unsigned* off = (unsigned*)(ws + off_b);
    off_b += (((size_t)(M + 1) * 4) + 255) & ~(size_t)255;
    unsigned* bsum = (unsigned*)(ws + off_b);
    off_b += 256;
    unsigned* bsumo = (unsigned*)(ws + off_b);
    off_b += 256;
    unsigned* recs = (unsigned*)(ws + off_b);

    const int nb = (M + 1023) / 1024;   // 49 scan blocks (<= 64)

    // counting sort of edges by dst
    rgcn_zero<<<(M + 255) / 256, 256, 0, stream>>>(cnt, M);
    rgcn_hist<<<(E + 255) / 256, 256, 0, stream>>>(edge_index, cnt, E);
    rgcn_scan1<<<nb, 1024, 0, stream>>>(cnt, off, bsum, M);
    rgcn_scan2<<<1, 64, 0, stream>>>(bsum, bsumo, off, nb, M);
    rgcn_scan3<<<(M + 255) / 256, 256, 0, stream>>>(off, bsumo, cnt, M);
    rgcn_scatter<<<(E + 255) / 256, 256, 0, stream>>>(edge_index, edge_type, cnt, recs, E);

    // bf16 x into Zcat[:, 2048:2304]; weights transposed+scaled
    rgcn_cvt<<<(M + 3) / 4, 256, 0, stream>>>(x, Zcat, M);
    rgcn_wbt<<<dim3(9, 256), 256, 0, stream>>>(weight, loop_w, wbT);

    // per-dst register aggregation -> Zcat[:, 0:2048]
    rgcn_agg<<<(M + 3) / 4, 256, 0, stream>>>(recs, off, Zcat, M);

    // single fused GEMM -> out
    rgcn_gemm<<<dim3(2, (M + BM - 1) / BM), 256, 0, stream>>>(Zcat, wbT, out, h_bias, M);
}